// Round 2
// baseline (484.102 us; speedup 1.0000x reference)
//
#include <hip/hip_runtime.h>

// GAP-TV CASSI reconstruction, H=W=512, L=28, 12 iterations, sigma=0.5 Gaussian.
// Dispersion offsets resolve to dx[l]=l, dy[l]=0  (rint of s*cos(1deg), s*sin(1deg)).
#define HH 512
#define WW 512
#define LL 28
#define WP 539              // W + dx_max (27)
#define NPIX (HH * WP)      // 512*539 = 275968
#define NX (LL * HH * WW)   // 28*512*512

#define TX 64
#define TY 16
#define GB 7                // bands per block group
#define NGRP (LL / GB)      // 4

// ---------------- setup: phi_inv = 1/max(sum_l mask_shift, 1);  y1 = y ----------------
__global__ void k_setup(const float* __restrict__ y, const float* __restrict__ mask,
                        float* __restrict__ phi_inv, float* __restrict__ y1) {
    int idx = blockIdx.x * blockDim.x + threadIdx.x;
    if (idx >= NPIX) return;
    int i = idx / WP, jp = idx - i * WP;
    int lmin = jp - (WW - 1); if (lmin < 0) lmin = 0;
    int lmax = jp < (LL - 1) ? jp : (LL - 1);
    float s = 0.f;
    for (int l = lmin; l <= lmax; ++l) s += mask[i * WW + (jp - l)];
    phi_inv[idx] = 1.0f / fmaxf(s, 1.0f);
    y1[idx] = y[idx];
}

// ---------------- x0 = At(y), and accumulate yb0 = A(x0) via LDS-reduced atomics ----------------
__global__ void k_xinit(const float* __restrict__ y, const float* __restrict__ mask,
                        float* __restrict__ x, float* __restrict__ yb) {
    __shared__ float ybl[TY][TX + GB - 1];
    const int l0 = blockIdx.z * GB;
    const int bi = blockIdx.y * TY;
    const int bj = blockIdx.x * TX;
    const int tid = threadIdx.x;       // 256

    for (int idx = tid; idx < TY * (TX + GB - 1); idx += 256)
        ybl[idx / (TX + GB - 1)][idx % (TX + GB - 1)] = 0.f;
    __syncthreads();

    for (int l = l0; l < l0 + GB; ++l) {
        #pragma unroll
        for (int k = 0; k < 4; ++k) {
            int idx = tid + k * 256;           // TY*TX = 1024
            int r = idx / TX, c = idx - r * TX;
            int gi = bi + r, gj = bj + c;
            float m = mask[gi * WW + gj];
            float v = y[gi * WP + gj + l] * m;
            x[((size_t)l * HH + gi) * WW + gj] = v;
            ybl[r][c + (l - l0)] += m * v;
        }
        __syncthreads();
    }
    for (int idx = tid; idx < TY * (TX + GB - 1); idx += 256) {
        int r = idx / (TX + GB - 1), c = idx % (TX + GB - 1);
        atomicAdd(&yb[(bi + r) * WP + bj + l0 + c], ybl[r][c]);
    }
}

// ---------------- per-iteration pixel step (float4): consume yb, update y1, produce t, re-zero yb --------
__global__ void k_pix(const float* __restrict__ y, const float* __restrict__ phi_inv,
                      float* __restrict__ y1, float* __restrict__ t, float* __restrict__ yb) {
    int idx = blockIdx.x * blockDim.x + threadIdx.x;
    if (idx >= NPIX / 4) return;
    float4 ybv = ((const float4*)yb)[idx];
    float4 yv  = ((const float4*)y)[idx];
    float4 y1v = ((const float4*)y1)[idx];
    float4 pv  = ((const float4*)phi_inv)[idx];
    float4 y1n, tv;
    y1n.x = y1v.x + yv.x - ybv.x;  tv.x = (y1n.x - ybv.x) * pv.x;
    y1n.y = y1v.y + yv.y - ybv.y;  tv.y = (y1n.y - ybv.y) * pv.y;
    y1n.z = y1v.z + yv.z - ybv.z;  tv.z = (y1n.z - ybv.z) * pv.z;
    y1n.w = y1v.w + yv.w - ybv.w;  tv.w = (y1n.w - ybv.w) * pv.w;
    ((float4*)y1)[idx] = y1n;
    ((float4*)t)[idx]  = tv;
    ((float4*)yb)[idx] = make_float4(0.f, 0.f, 0.f, 0.f);   // ready for next accumulation
}

// ---------------- fused: xo = blur5x5( x + At(t) ); yb += A(xo)  (LDS-reduced) ----------------
template <bool LAST>
__global__ void k_iter(const float* __restrict__ x, const float* __restrict__ t,
                       const float* __restrict__ mask, float* __restrict__ xo,
                       float* __restrict__ yb, float w0, float w1, float w2) {
    __shared__ float msk[TY + 4][TX + 4];
    __shared__ float u[TY + 4][TX + 4];
    __shared__ float hb[TY + 4][TX];
    __shared__ float ybl[TY][TX + GB - 1];

    const int l0 = blockIdx.z * GB;
    const int bi = blockIdx.y * TY;
    const int bj = blockIdx.x * TX;
    const int tid = threadIdx.x;      // 256

    // stage mask tile with 2-halo (zero outside), zero ybl
    for (int idx = tid; idx < (TY + 4) * (TX + 4); idx += 256) {
        int r = idx / (TX + 4), c = idx - r * (TX + 4);
        int gi = bi + r - 2, gj = bj + c - 2;
        msk[r][c] = (gi >= 0 && gi < HH && gj >= 0 && gj < WW) ? mask[gi * WW + gj] : 0.f;
    }
    if (!LAST)
        for (int idx = tid; idx < TY * (TX + GB - 1); idx += 256)
            ybl[idx / (TX + GB - 1)][idx % (TX + GB - 1)] = 0.f;
    __syncthreads();

    for (int l = l0; l < l0 + GB; ++l) {
        const float* xl = x + (size_t)l * HH * WW;
        // u = x + At(t), 2-halo
        for (int idx = tid; idx < (TY + 4) * (TX + 4); idx += 256) {
            int r = idx / (TX + 4), c = idx - r * (TX + 4);
            int gi = bi + r - 2, gj = bj + c - 2;
            float v = 0.f;
            if (gi >= 0 && gi < HH && gj >= 0 && gj < WW)
                v = xl[gi * WW + gj] + t[gi * WP + gj + l] * msk[r][c];
            u[r][c] = v;
        }
        __syncthreads();
        // horizontal blur
        for (int idx = tid; idx < (TY + 4) * TX; idx += 256) {
            int r = idx / TX, c = idx - r * TX;
            hb[r][c] = w2 * (u[r][c] + u[r][c + 4])
                     + w1 * (u[r][c + 1] + u[r][c + 3])
                     + w0 * u[r][c + 2];
        }
        __syncthreads();
        // vertical blur + store + forward-scatter accumulate
        #pragma unroll
        for (int k = 0; k < 4; ++k) {
            int idx = tid + k * 256;          // TY*TX = 1024
            int r = idx / TX, c = idx - r * TX;
            float o = w2 * (hb[r][c] + hb[r + 4][c])
                    + w1 * (hb[r + 1][c] + hb[r + 3][c])
                    + w0 * hb[r + 2][c];
            xo[((size_t)l * HH + bi + r) * WW + bj + c] = o;
            if (!LAST) ybl[r][c + (l - l0)] += msk[r + 2][c + 2] * o;
        }
        __syncthreads();
    }

    if (!LAST)
        for (int idx = tid; idx < TY * (TX + GB - 1); idx += 256) {
            int r = idx / (TX + GB - 1), c = idx % (TX + GB - 1);
            atomicAdd(&yb[(bi + r) * WP + bj + l0 + c], ybl[r][c]);
        }
}

extern "C" void kernel_launch(void* const* d_in, const int* in_sizes, int n_in,
                              void* d_out, int out_size, void* d_ws, size_t ws_size,
                              hipStream_t stream) {
    const float* y    = (const float*)d_in[0];   // [1, 512, 539]
    const float* mask = (const float*)d_in[1];   // [512, 512]

    float* out = (float*)d_out;                  // [1, 28, 512, 512] == x ping-pong B

    float* phi_inv = (float*)d_ws;               // NPIX
    float* y1      = phi_inv + NPIX;             // NPIX
    float* t       = y1 + NPIX;                  // NPIX
    float* yb      = t + NPIX;                   // NPIX
    float* xA      = yb + NPIX;                  // NX (ping-pong A)
    float* xB      = out;

    // Gaussian weights (sigma = 0.5, ksize = 5)
    float g1 = expf(-2.0f), g2 = expf(-8.0f);
    float gs = 1.0f + 2.0f * g1 + 2.0f * g2;
    float w0 = 1.0f / gs, w1 = g1 / gs, w2 = g2 / gs;

    const int BT = 256;
    const dim3 tgrid(WW / TX, HH / TY, NGRP);

    hipMemsetAsync(yb, 0, NPIX * sizeof(float), stream);
    k_setup<<<(NPIX + BT - 1) / BT, BT, 0, stream>>>(y, mask, phi_inv, y1);
    k_xinit<<<tgrid, BT, 0, stream>>>(y, mask, xB, yb);

    float* cur = xB;
    float* nxt = xA;
    for (int it = 0; it < 12; ++it) {
        k_pix<<<(NPIX / 4 + BT - 1) / BT, BT, 0, stream>>>(y, phi_inv, y1, t, yb);
        if (it < 11)
            k_iter<false><<<tgrid, BT, 0, stream>>>(cur, t, mask, nxt, yb, w0, w1, w2);
        else
            k_iter<true><<<tgrid, BT, 0, stream>>>(cur, t, mask, nxt, yb, w0, w1, w2);
        float* tmp = cur; cur = nxt; nxt = tmp;
    }
    // 12 swaps: final write landed in xB == d_out.
}